// Round 1
// baseline (841.368 us; speedup 1.0000x reference)
//
#include <hip/hip_runtime.h>
#include <hip/hip_bf16.h>
#include <math.h>

#define Hdim 1024
#define Vdim 50257
#define Bdim 64
#define Tdim 2048

#define TCH 64
#define NCHUNK (Tdim / TCH)  // 32
#define PSTRIDE (Hdim + 4)

// ---------------- embed + concat ----------------
__global__ void k_embed_concat(const int* __restrict__ idx, const float* __restrict__ E,
                               const float* __restrict__ context,
                               float* __restrict__ x, float* __restrict__ emb) {
  int i = blockIdx.x * blockDim.x + threadIdx.x;
  if (i >= Bdim * Hdim) return;
  int b = i >> 10, h = i & 1023;
  float e = E[(long)idx[b] * Hdim + h];
  emb[i] = e;
  x[(long)b * 2 * Hdim + h] = e;
  x[(long)b * 2 * Hdim + Hdim + h] = context[i];
}

// ---------------- GRU gate fusion ----------------
__global__ void k_gru_gate(const float* __restrict__ gi, const float* __restrict__ gh,
                           const float* __restrict__ hprev, float* __restrict__ hout) {
  int i = blockIdx.x * blockDim.x + threadIdx.x;
  if (i >= Bdim * Hdim) return;
  int b = i >> 10, h = i & 1023;
  const float* gib = gi + (long)b * 3 * Hdim;
  const float* ghb = gh + (long)b * 3 * Hdim;
  float ir = gib[h], iz = gib[Hdim + h], in = gib[2 * Hdim + h];
  float hr = ghb[h], hz = ghb[Hdim + h], hn = ghb[2 * Hdim + h];
  float r = 1.f / (1.f + __expf(-(ir + hr)));
  float z = 1.f / (1.f + __expf(-(iz + hz)));
  float n = tanhf(in + r * hn);
  hout[i] = (1.f - z) * n + z * hprev[i];
}

// ---------------- generic M=64 tiled fp32 GEMM ----------------
// C[64, N] = A[64, K] @ op(W) + bias, op(W)=W.T for TRANSW=false (W is [N,K]),
// op(W)=W for TRANSW=true (W is [K,N]). ACT: 0 none, 1 tanh.
template <int ACT, bool TRANSW>
__global__ void k_gemm_m64(const float* __restrict__ A, int lda,
                           const float* __restrict__ W, int ldw,
                           const float* __restrict__ bias,
                           float* __restrict__ C, int ldc, int N, int K) {
  __shared__ float As[16][68];  // [k][m], padded to break bank conflicts
  __shared__ float Ws[16][68];  // [k][n]
  int tid = threadIdx.x;
  int tx = tid & 15, ty = tid >> 4;
  int n0 = blockIdx.x * 64;
  float acc[4][4];
#pragma unroll
  for (int i = 0; i < 4; i++)
#pragma unroll
    for (int j = 0; j < 4; j++) acc[i][j] = 0.f;

  for (int k0 = 0; k0 < K; k0 += 16) {
    {
      int m = tid >> 2;
      int kk = (tid & 3) << 2;
      float4 av = *(const float4*)(A + (long)m * lda + k0 + kk);
      As[kk + 0][m] = av.x; As[kk + 1][m] = av.y;
      As[kk + 2][m] = av.z; As[kk + 3][m] = av.w;
    }
    if (!TRANSW) {
      int n = tid >> 2;
      int kk = (tid & 3) << 2;
      long gn = n0 + n;
      float4 wv = make_float4(0.f, 0.f, 0.f, 0.f);
      if (gn < N) wv = *(const float4*)(W + gn * (long)ldw + k0 + kk);
      Ws[kk + 0][n] = wv.x; Ws[kk + 1][n] = wv.y;
      Ws[kk + 2][n] = wv.z; Ws[kk + 3][n] = wv.w;
    } else {
      int kk = tid >> 4;
      int n4 = (tid & 15) << 2;
      float4 wv = *(const float4*)(W + (long)(k0 + kk) * ldw + n0 + n4);
      *(float4*)&Ws[kk][n4] = wv;
    }
    __syncthreads();
#pragma unroll
    for (int k = 0; k < 16; ++k) {
      float4 a = *(const float4*)&As[k][ty << 2];
      float4 w = *(const float4*)&Ws[k][tx << 2];
      acc[0][0] += a.x * w.x; acc[0][1] += a.x * w.y; acc[0][2] += a.x * w.z; acc[0][3] += a.x * w.w;
      acc[1][0] += a.y * w.x; acc[1][1] += a.y * w.y; acc[1][2] += a.y * w.z; acc[1][3] += a.y * w.w;
      acc[2][0] += a.z * w.x; acc[2][1] += a.z * w.y; acc[2][2] += a.z * w.z; acc[2][3] += a.z * w.w;
      acc[3][0] += a.w * w.x; acc[3][1] += a.w * w.y; acc[3][2] += a.w * w.z; acc[3][3] += a.w * w.w;
    }
    __syncthreads();
  }
#pragma unroll
  for (int i = 0; i < 4; i++) {
    int m = (ty << 2) + i;
#pragma unroll
    for (int j = 0; j < 4; j++) {
      int n = n0 + (tx << 2) + j;
      if (n < N) {
        float v = acc[i][j];
        if (bias) v += bias[n];
        if (ACT == 1) v = tanhf(v);
        C[(long)m * ldc + n] = v;
      }
    }
  }
}

// ---------------- cb[b] = h1[b,:] . ba ----------------
__global__ void k_cb(const float* __restrict__ h1, const float* __restrict__ ba,
                     float* __restrict__ cb) {
  int b = blockIdx.x;
  int tid = threadIdx.x;  // 256
  float p = 0.f;
  for (int h = tid; h < Hdim; h += 256) p += h1[(long)b * Hdim + h] * ba[h];
#pragma unroll
  for (int off = 32; off > 0; off >>= 1) p += __shfl_down(p, off, 64);
  __shared__ float red[4];
  if ((tid & 63) == 0) red[tid >> 6] = p;
  __syncthreads();
  if (tid == 0) cb[b] = red[0] + red[1] + red[2] + red[3];
}

// ---------------- single pass over enc: scores + online-softmax partial context ----
__global__ void k_scores_ctx(const float* __restrict__ enc, const float* __restrict__ q,
                             const float* __restrict__ cb, float* __restrict__ scores,
                             float* __restrict__ part) {
  int b = blockIdx.y, ch = blockIdx.x;
  int tid = threadIdx.x;  // 256, each owns 4 h-positions (float4)
  __shared__ float red[4];
  float4 qv = ((const float4*)(q + (long)b * Hdim))[tid];
  float cbb = cb[b];
  float m = -INFINITY, l = 0.f;
  float4 acc = make_float4(0.f, 0.f, 0.f, 0.f);
  int t0 = ch * TCH;
  for (int t = t0; t < t0 + TCH; ++t) {
    float4 e = ((const float4*)(enc + ((long)t * Bdim + b) * Hdim))[tid];
    float p = qv.x * e.x + qv.y * e.y + qv.z * e.z + qv.w * e.w;
#pragma unroll
    for (int off = 32; off > 0; off >>= 1) p += __shfl_down(p, off, 64);
    __syncthreads();
    if ((tid & 63) == 0) red[tid >> 6] = p;
    __syncthreads();
    float s = red[0] + red[1] + red[2] + red[3] + cbb;
    if (tid == 0) scores[(long)b * Tdim + t] = s;
    float mn = fmaxf(m, s);
    float sc = __expf(m - mn);   // exp(-inf)=0 on first iter
    float w = __expf(s - mn);
    l = l * sc + w;
    acc.x = acc.x * sc + w * e.x;
    acc.y = acc.y * sc + w * e.y;
    acc.z = acc.z * sc + w * e.z;
    acc.w = acc.w * sc + w * e.w;
    m = mn;
  }
  float* pp = part + ((long)b * NCHUNK + ch) * PSTRIDE;
  ((float4*)pp)[tid] = acc;
  if (tid == 0) { pp[Hdim] = m; pp[Hdim + 1] = l; }
}

// ---------------- combine partials -> context, write m/l ----------------
__global__ void k_ctx_combine(const float* __restrict__ part, float* __restrict__ ctx_out,
                              float* __restrict__ cat, float* __restrict__ ml) {
  int b = blockIdx.x, tid = threadIdx.x;  // 256
  __shared__ float ms[NCHUNK], ls[NCHUNK];
  if (tid < NCHUNK) {
    const float* pp = part + ((long)b * NCHUNK + tid) * PSTRIDE;
    ms[tid] = pp[Hdim];
    ls[tid] = pp[Hdim + 1];
  }
  __syncthreads();
  float m = -INFINITY;
  for (int c = 0; c < NCHUNK; ++c) m = fmaxf(m, ms[c]);
  float l = 0.f;
  for (int c = 0; c < NCHUNK; ++c) l += __expf(ms[c] - m) * ls[c];
  float4 a = make_float4(0.f, 0.f, 0.f, 0.f);
  for (int c = 0; c < NCHUNK; ++c) {
    float w = __expf(ms[c] - m);
    float4 v = ((const float4*)(part + ((long)b * NCHUNK + c) * PSTRIDE))[tid];
    a.x += w * v.x; a.y += w * v.y; a.z += w * v.z; a.w += w * v.w;
  }
  float inv = 1.f / l;
  a.x *= inv; a.y *= inv; a.z *= inv; a.w *= inv;
  ((float4*)(ctx_out + (long)b * Hdim))[tid] = a;
  ((float4*)(cat + (long)b * 2 * Hdim + Hdim))[tid] = a;
  if (tid == 0) { ml[2 * b] = m; ml[2 * b + 1] = l; }
}

// ---------------- attn weights output ----------------
__global__ void k_attn(const float* __restrict__ scores, const float* __restrict__ ml,
                       float* __restrict__ attn) {
  int i = blockIdx.x * blockDim.x + threadIdx.x;
  if (i >= Bdim * Tdim) return;
  int b = i >> 11;  // T=2048
  attn[i] = __expf(scores[i] - ml[2 * b]) / ml[2 * b + 1];
}

// ---------------- new_hidden = stack(h0,h1) + emb ----------------
__global__ void k_hidden_out(const float* __restrict__ h0, const float* __restrict__ h1,
                             const float* __restrict__ emb, float* __restrict__ out) {
  int i = blockIdx.x * blockDim.x + threadIdx.x;
  if (i >= 2 * Bdim * Hdim) return;
  int r = i & (Bdim * Hdim - 1);
  float hv = (i < Bdim * Hdim) ? h0[r] : h1[r];
  out[i] = hv + emb[r];
}

// ---------------- copy h1 into cat[:, 0:H] ----------------
__global__ void k_copy_h1_cat(const float* __restrict__ h1, float* __restrict__ cat) {
  int i = blockIdx.x * blockDim.x + threadIdx.x;
  if (i >= Bdim * Hdim) return;
  int b = i >> 10, h = i & 1023;
  cat[(long)b * 2 * Hdim + h] = h1[i];
}

// ---------------- in-place row log_softmax over [B, V] ----------------
__global__ void k_logsoftmax(float* __restrict__ out) {
  int b = blockIdx.x;
  int tid = threadIdx.x;  // 1024
  float* row = out + (long)b * Vdim;
  __shared__ float red[16];
  float mx = -INFINITY;
  for (int v = tid; v < Vdim; v += 1024) mx = fmaxf(mx, row[v]);
#pragma unroll
  for (int off = 32; off > 0; off >>= 1) mx = fmaxf(mx, __shfl_down(mx, off, 64));
  if ((tid & 63) == 0) red[tid >> 6] = mx;
  __syncthreads();
  float m2 = -INFINITY;
  for (int i = 0; i < 16; i++) m2 = fmaxf(m2, red[i]);
  float s = 0.f;
  for (int v = tid; v < Vdim; v += 1024) s += __expf(row[v] - m2);
#pragma unroll
  for (int off = 32; off > 0; off >>= 1) s += __shfl_down(s, off, 64);
  __syncthreads();  // everyone done reading red (max)
  if ((tid & 63) == 0) red[tid >> 6] = s;
  __syncthreads();
  float s2 = 0.f;
  for (int i = 0; i < 16; i++) s2 += red[i];
  float lg = m2 + logf(s2);
  for (int v = tid; v < Vdim; v += 1024) row[v] = row[v] - lg;
}

extern "C" void kernel_launch(void* const* d_in, const int* in_sizes, int n_in,
                              void* d_out, int out_size, void* d_ws, size_t ws_size,
                              hipStream_t stream) {
  const int* inputs   = (const int*)d_in[0];
  const float* hidden = (const float*)d_in[1];
  const float* context= (const float*)d_in[2];
  const float* enc    = (const float*)d_in[3];
  const float* E      = (const float*)d_in[4];
  const float* W_ih0  = (const float*)d_in[5];
  const float* W_hh0  = (const float*)d_in[6];
  const float* b_ih0  = (const float*)d_in[7];
  const float* b_hh0  = (const float*)d_in[8];
  const float* W_ih1  = (const float*)d_in[9];
  const float* W_hh1  = (const float*)d_in[10];
  const float* b_ih1  = (const float*)d_in[11];
  const float* b_hh1  = (const float*)d_in[12];
  const float* Wa     = (const float*)d_in[13];
  const float* ba     = (const float*)d_in[14];
  const float* Wo     = (const float*)d_in[15];
  const float* bo     = (const float*)d_in[16];

  float* ws = (float*)d_ws;
  float* x_buf   = ws;                       // 131072
  float* emb     = x_buf + 131072;           // 65536
  float* gi      = emb + 65536;              // 196608
  float* gh      = gi + 196608;              // 196608
  float* h0      = gh + 196608;              // 65536
  float* h1      = h0 + 65536;               // 65536
  float* q       = h1 + 65536;               // 65536
  float* cat     = q + 65536;                // 131072
  float* scoresp = cat + 131072;             // 131072
  float* cbp     = scoresp + 131072;         // 64
  float* ml      = cbp + 64;                 // 128
  float* part    = ml + 128;                 // 64*32*PSTRIDE = 2,105,344

  float* out0 = (float*)d_out;                       // [B, V] log-softmax
  float* out1 = out0 + (size_t)Bdim * Vdim;          // [2, B, H] new_hidden
  float* out2 = out1 + (size_t)2 * Bdim * Hdim;      // [B, H] new_context
  float* out3 = out2 + (size_t)Bdim * Hdim;          // [B, T] attn

  k_embed_concat<<<256, 256, 0, stream>>>(inputs, E, context, x_buf, emb);

  // GRU layer 0
  k_gemm_m64<0, false><<<48, 256, 0, stream>>>(x_buf, 2 * Hdim, W_ih0, 2 * Hdim, b_ih0, gi, 3 * Hdim, 3 * Hdim, 2 * Hdim);
  k_gemm_m64<0, false><<<48, 256, 0, stream>>>(hidden, Hdim, W_hh0, Hdim, b_hh0, gh, 3 * Hdim, 3 * Hdim, Hdim);
  k_gru_gate<<<256, 256, 0, stream>>>(gi, gh, hidden, h0);

  // GRU layer 1
  k_gemm_m64<0, false><<<48, 256, 0, stream>>>(h0, Hdim, W_ih1, Hdim, b_ih1, gi, 3 * Hdim, 3 * Hdim, Hdim);
  k_gemm_m64<0, false><<<48, 256, 0, stream>>>(hidden + Bdim * Hdim, Hdim, W_hh1, Hdim, b_hh1, gh, 3 * Hdim, 3 * Hdim, Hdim);
  k_gru_gate<<<256, 256, 0, stream>>>(gi, gh, hidden + Bdim * Hdim, h1);

  k_hidden_out<<<512, 256, 0, stream>>>(h0, h1, emb, out1);
  k_copy_h1_cat<<<256, 256, 0, stream>>>(h1, cat);

  // q = h1 @ Wa  (Wa is [H,H] row-major [j,k]; need sum_j h1[b,j]*Wa[j,n])
  k_gemm_m64<0, true><<<16, 256, 0, stream>>>(h1, Hdim, Wa, Hdim, nullptr, q, Hdim, Hdim, Hdim);
  k_cb<<<64, 256, 0, stream>>>(h1, ba, cbp);

  dim3 gsc(NCHUNK, Bdim);
  k_scores_ctx<<<gsc, 256, 0, stream>>>(enc, q, cbp, scoresp, part);
  k_ctx_combine<<<64, 256, 0, stream>>>(part, out2, cat, ml);
  k_attn<<<512, 256, 0, stream>>>(scoresp, ml, out3);

  // logits = tanh(cat @ Wo.T + bo) -> out0, then log_softmax in place
  k_gemm_m64<1, false><<<786, 256, 0, stream>>>(cat, 2 * Hdim, Wo, 2 * Hdim, bo, out0, Vdim, Vdim, 2 * Hdim);
  k_logsoftmax<<<64, 1024, 0, stream>>>(out0);
}

// Round 2
// 452.676 us; speedup vs baseline: 1.8587x; 1.8587x over previous
//
#include <hip/hip_runtime.h>
#include <hip/hip_bf16.h>
#include <math.h>

#define Hdim 1024
#define Vdim 50257
#define Bdim 64
#define Tdim 2048

#define TCH 64
#define NCHUNK (Tdim / TCH)  // 32
#define PSTRIDE (Hdim + 4)

typedef short bf16x8 __attribute__((ext_vector_type(8)));
typedef float f32x4 __attribute__((ext_vector_type(4)));

__device__ __forceinline__ unsigned short f2bf(float f) {
  unsigned int u = __float_as_uint(f);
  unsigned int r = u + 0x7FFFu + ((u >> 16) & 1u);  // RNE
  return (unsigned short)(r >> 16);
}

// ---------------- embed + concat ----------------
__global__ void k_embed_concat(const int* __restrict__ idx, const float* __restrict__ E,
                               const float* __restrict__ context,
                               float* __restrict__ x, float* __restrict__ emb) {
  int i = blockIdx.x * blockDim.x + threadIdx.x;
  if (i >= Bdim * Hdim) return;
  int b = i >> 10, h = i & 1023;
  float e = E[(long)idx[b] * Hdim + h];
  emb[i] = e;
  x[(long)b * 2 * Hdim + h] = e;
  x[(long)b * 2 * Hdim + Hdim + h] = context[i];
}

// ---------------- split-K fp32 GEMM, M=64 tile, N tile 64 ----------------
// Cpart[sk][64][ldc] partial = A[64, kBase:kBase+kLen] @ op(W)
template <bool TRANSW>
__global__ void k_gemm_sk(const float* __restrict__ A, int lda,
                          const float* __restrict__ W, int ldw,
                          float* __restrict__ Cpart, int ldc, int N, int kLen) {
  __shared__ float As[16][68];
  __shared__ float Ws[16][68];
  int tid = threadIdx.x;
  int tx = tid & 15, ty = tid >> 4;
  int n0 = blockIdx.x * 64;
  int kBase = blockIdx.y * kLen;
  float acc[4][4];
#pragma unroll
  for (int i = 0; i < 4; i++)
#pragma unroll
    for (int j = 0; j < 4; j++) acc[i][j] = 0.f;

  for (int k0 = kBase; k0 < kBase + kLen; k0 += 16) {
    {
      int m = tid >> 2;
      int kk = (tid & 3) << 2;
      float4 av = *(const float4*)(A + (long)m * lda + k0 + kk);
      As[kk + 0][m] = av.x; As[kk + 1][m] = av.y;
      As[kk + 2][m] = av.z; As[kk + 3][m] = av.w;
    }
    if (!TRANSW) {
      int n = tid >> 2;
      int kk = (tid & 3) << 2;
      long gn = n0 + n;
      float4 wv = make_float4(0.f, 0.f, 0.f, 0.f);
      if (gn < N) wv = *(const float4*)(W + gn * (long)ldw + k0 + kk);
      Ws[kk + 0][n] = wv.x; Ws[kk + 1][n] = wv.y;
      Ws[kk + 2][n] = wv.z; Ws[kk + 3][n] = wv.w;
    } else {
      int kk = tid >> 4;
      int n4 = (tid & 15) << 2;
      float4 wv = *(const float4*)(W + (long)(k0 + kk) * ldw + n0 + n4);
      *(float4*)&Ws[kk][n4] = wv;
    }
    __syncthreads();
#pragma unroll
    for (int k = 0; k < 16; ++k) {
      float4 a = *(const float4*)&As[k][ty << 2];
      float4 w = *(const float4*)&Ws[k][tx << 2];
      acc[0][0] += a.x * w.x; acc[0][1] += a.x * w.y; acc[0][2] += a.x * w.z; acc[0][3] += a.x * w.w;
      acc[1][0] += a.y * w.x; acc[1][1] += a.y * w.y; acc[1][2] += a.y * w.z; acc[1][3] += a.y * w.w;
      acc[2][0] += a.z * w.x; acc[2][1] += a.z * w.y; acc[2][2] += a.z * w.z; acc[2][3] += a.z * w.w;
      acc[3][0] += a.w * w.x; acc[3][1] += a.w * w.y; acc[3][2] += a.w * w.z; acc[3][3] += a.w * w.w;
    }
    __syncthreads();
  }
  float* C = Cpart + (long)blockIdx.y * 64 * ldc;
#pragma unroll
  for (int i = 0; i < 4; i++) {
    int m = (ty << 2) + i;
#pragma unroll
    for (int j = 0; j < 4; j++) {
      int n = n0 + (tx << 2) + j;
      if (n < N) C[(long)m * ldc + n] = acc[i][j];
    }
  }
}

// ---------------- GRU gate fusion + split-K combine ----------------
__global__ void k_gru_gate2(const float* __restrict__ gi_part, int ski,
                            const float* __restrict__ gh_part, int skh,
                            const float* __restrict__ b_ih, const float* __restrict__ b_hh,
                            const float* __restrict__ hprev, float* __restrict__ hout) {
  int i = blockIdx.x * blockDim.x + threadIdx.x;
  if (i >= Bdim * Hdim) return;
  int b = i >> 10, h = i & 1023;
  float ir = b_ih[h], iz = b_ih[Hdim + h], in = b_ih[2 * Hdim + h];
  float hr = b_hh[h], hz = b_hh[Hdim + h], hn = b_hh[2 * Hdim + h];
  for (int s = 0; s < ski; ++s) {
    const float* g = gi_part + ((long)s * 64 + b) * 3072;
    ir += g[h]; iz += g[Hdim + h]; in += g[2 * Hdim + h];
  }
  for (int s = 0; s < skh; ++s) {
    const float* g = gh_part + ((long)s * 64 + b) * 3072;
    hr += g[h]; hz += g[Hdim + h]; hn += g[2 * Hdim + h];
  }
  float r = 1.f / (1.f + __expf(-(ir + hr)));
  float z = 1.f / (1.f + __expf(-(iz + hz)));
  float n = tanhf(in + r * hn);
  hout[i] = (1.f - z) * n + z * hprev[i];
}

// ---------------- q = sum of split-K partials ----------------
__global__ void k_qcomb(const float* __restrict__ qp, float* __restrict__ q) {
  int i = blockIdx.x * 256 + threadIdx.x;  // 65536 total
  float s = 0.f;
#pragma unroll
  for (int k = 0; k < 8; ++k) s += qp[(long)k * 65536 + i];
  q[i] = s;
}

// ---------------- cb[b] = h1[b,:] . ba ----------------
__global__ void k_cb(const float* __restrict__ h1, const float* __restrict__ ba,
                     float* __restrict__ cb) {
  int b = blockIdx.x;
  int tid = threadIdx.x;  // 256
  float p = 0.f;
  for (int h = tid; h < Hdim; h += 256) p += h1[(long)b * Hdim + h] * ba[h];
#pragma unroll
  for (int off = 32; off > 0; off >>= 1) p += __shfl_down(p, off, 64);
  __shared__ float red[4];
  if ((tid & 63) == 0) red[tid >> 6] = p;
  __syncthreads();
  if (tid == 0) cb[b] = red[0] + red[1] + red[2] + red[3];
}

// ---------------- h1 -> catb (bf16) cols [0,H) ----------------
__global__ void k_h1_to_catb(const float* __restrict__ h1, unsigned short* __restrict__ catb) {
  int i = blockIdx.x * blockDim.x + threadIdx.x;  // 16384
  if (i >= Bdim * Hdim / 4) return;
  int b = i >> 8, p = i & 255;
  float4 v = ((const float4*)(h1 + (long)b * Hdim))[p];
  ushort4 o;
  o.x = f2bf(v.x); o.y = f2bf(v.y); o.z = f2bf(v.z); o.w = f2bf(v.w);
  *(ushort4*)(catb + (long)b * 2 * Hdim + p * 4) = o;
}

// ---------------- scores + online-softmax partial context (wave-per-row) ----
__global__ __launch_bounds__(256) void k_scores_ctx(
    const float* __restrict__ enc, const float* __restrict__ q,
    const float* __restrict__ cb, float* __restrict__ scores,
    float* __restrict__ part) {
  int b = blockIdx.y, ch = blockIdx.x;
  int tid = threadIdx.x, w = tid >> 6, lane = tid & 63;
  __shared__ float s_acc[4][Hdim];
  __shared__ float s_ml[4][2];
  const float4* q4 = (const float4*)(q + (long)b * Hdim);
  float4 q0 = q4[lane], q1 = q4[lane + 64], q2 = q4[lane + 128], q3 = q4[lane + 192];
  float cbb = cb[b];
  float m = -INFINITY, l = 0.f;
  float4 a0 = make_float4(0, 0, 0, 0), a1 = a0, a2 = a0, a3 = a0;
  int tbase = ch * TCH + w * 16;
  for (int i = 0; i < 16; ++i) {
    int t = tbase + i;
    const float4* e4 = (const float4*)(enc + ((long)t * Bdim + b) * Hdim);
    float4 e0 = e4[lane], e1 = e4[lane + 64], e2 = e4[lane + 128], e3 = e4[lane + 192];
    float p = q0.x * e0.x + q0.y * e0.y + q0.z * e0.z + q0.w * e0.w
            + q1.x * e1.x + q1.y * e1.y + q1.z * e1.z + q1.w * e1.w
            + q2.x * e2.x + q2.y * e2.y + q2.z * e2.z + q2.w * e2.w
            + q3.x * e3.x + q3.y * e3.y + q3.z * e3.z + q3.w * e3.w;
#pragma unroll
    for (int off = 1; off < 64; off <<= 1) p += __shfl_xor(p, off, 64);
    float s = p + cbb;
    if (lane == 0) scores[(long)b * Tdim + t] = s;
    float mn = fmaxf(m, s);
    float sc = __expf(m - mn);  // exp(-inf)=0 on first iter
    float wt = __expf(s - mn);
    l = l * sc + wt;
    a0.x = a0.x * sc + wt * e0.x; a0.y = a0.y * sc + wt * e0.y;
    a0.z = a0.z * sc + wt * e0.z; a0.w = a0.w * sc + wt * e0.w;
    a1.x = a1.x * sc + wt * e1.x; a1.y = a1.y * sc + wt * e1.y;
    a1.z = a1.z * sc + wt * e1.z; a1.w = a1.w * sc + wt * e1.w;
    a2.x = a2.x * sc + wt * e2.x; a2.y = a2.y * sc + wt * e2.y;
    a2.z = a2.z * sc + wt * e2.z; a2.w = a2.w * sc + wt * e2.w;
    a3.x = a3.x * sc + wt * e3.x; a3.y = a3.y * sc + wt * e3.y;
    a3.z = a3.z * sc + wt * e3.z; a3.w = a3.w * sc + wt * e3.w;
    m = mn;
  }
  float4* sa = (float4*)s_acc[w];
  sa[lane] = a0; sa[lane + 64] = a1; sa[lane + 128] = a2; sa[lane + 192] = a3;
  if (lane == 0) { s_ml[w][0] = m; s_ml[w][1] = l; }
  __syncthreads();
  float M = fmaxf(fmaxf(s_ml[0][0], s_ml[1][0]), fmaxf(s_ml[2][0], s_ml[3][0]));
  float L = 0.f;
  float4 o = make_float4(0, 0, 0, 0);
  for (int ww = 0; ww < 4; ++ww) {
    float wgt = __expf(s_ml[ww][0] - M);
    L += wgt * s_ml[ww][1];
    float4 v = ((const float4*)s_acc[ww])[tid];
    o.x += wgt * v.x; o.y += wgt * v.y; o.z += wgt * v.z; o.w += wgt * v.w;
  }
  float* pp = part + ((long)b * NCHUNK + ch) * PSTRIDE;
  ((float4*)pp)[tid] = o;
  if (tid == 0) { pp[Hdim] = M; pp[Hdim + 1] = L; }
}

// ---------------- combine partials -> context (fp32 out + bf16 into catb) ----
__global__ void k_ctx_combine(const float* __restrict__ part, float* __restrict__ ctx_out,
                              unsigned short* __restrict__ catb, float* __restrict__ ml) {
  int b = blockIdx.x, tid = threadIdx.x;  // 256
  __shared__ float ms[NCHUNK], ls[NCHUNK];
  if (tid < NCHUNK) {
    const float* pp = part + ((long)b * NCHUNK + tid) * PSTRIDE;
    ms[tid] = pp[Hdim];
    ls[tid] = pp[Hdim + 1];
  }
  __syncthreads();
  float m = -INFINITY;
  for (int c = 0; c < NCHUNK; ++c) m = fmaxf(m, ms[c]);
  float l = 0.f;
  for (int c = 0; c < NCHUNK; ++c) l += __expf(ms[c] - m) * ls[c];
  float4 a = make_float4(0, 0, 0, 0);
  for (int c = 0; c < NCHUNK; ++c) {
    float w = __expf(ms[c] - m);
    float4 v = ((const float4*)(part + ((long)b * NCHUNK + c) * PSTRIDE))[tid];
    a.x += w * v.x; a.y += w * v.y; a.z += w * v.z; a.w += w * v.w;
  }
  float inv = 1.f / l;
  a.x *= inv; a.y *= inv; a.z *= inv; a.w *= inv;
  ((float4*)(ctx_out + (long)b * Hdim))[tid] = a;
  ushort4 o;
  o.x = f2bf(a.x); o.y = f2bf(a.y); o.z = f2bf(a.z); o.w = f2bf(a.w);
  *(ushort4*)(catb + (long)b * 2 * Hdim + Hdim + tid * 4) = o;
  if (tid == 0) { ml[2 * b] = m; ml[2 * b + 1] = l; }
}

// ---------------- attn weights output ----------------
__global__ void k_attn(const float* __restrict__ scores, const float* __restrict__ ml,
                       float* __restrict__ attn) {
  int i = blockIdx.x * blockDim.x + threadIdx.x;
  if (i >= Bdim * Tdim) return;
  int b = i >> 11;
  attn[i] = __expf(scores[i] - ml[2 * b]) / ml[2 * b + 1];
}

// ---------------- new_hidden = stack(h0,h1) + emb ----------------
__global__ void k_hidden_out(const float* __restrict__ h0, const float* __restrict__ h1,
                             const float* __restrict__ emb, float* __restrict__ out) {
  int i = blockIdx.x * blockDim.x + threadIdx.x;
  if (i >= 2 * Bdim * Hdim) return;
  int r = i & (Bdim * Hdim - 1);
  float hv = (i < Bdim * Hdim) ? h0[r] : h1[r];
  out[i] = hv + emb[r];
}

// ---------------- Wo GEMM: bf16 MFMA, fp32 Wo converted in load path ----------
// out[64, V] = tanh(catb[64, 2H] @ Wo[V, 2H].T + bo)
__global__ __launch_bounds__(256) void k_wo_mfma(const unsigned short* __restrict__ catb,
                                                 const float* __restrict__ Wo,
                                                 const float* __restrict__ bo,
                                                 float* __restrict__ out) {
  int tid = threadIdx.x, w = tid >> 6, lane = tid & 63;
  int n = blockIdx.x * 64 + w * 16 + (lane & 15);
  bool valid = n < Vdim;
  const float* wrow = Wo + (long)(valid ? n : 0) * (2 * Hdim);
  int kb = (lane >> 4) * 8;
  int r16 = lane & 15;
  const unsigned short* ar0 = catb + (long)(r16) * 2048 + kb;
  const unsigned short* ar1 = catb + (long)(16 + r16) * 2048 + kb;
  const unsigned short* ar2 = catb + (long)(32 + r16) * 2048 + kb;
  const unsigned short* ar3 = catb + (long)(48 + r16) * 2048 + kb;
  f32x4 acc0 = {0.f, 0.f, 0.f, 0.f}, acc1 = acc0, acc2 = acc0, acc3 = acc0;
#pragma unroll 2
  for (int k0 = 0; k0 < 2048; k0 += 32) {
    float4 w0 = *(const float4*)(wrow + k0 + kb);
    float4 w1 = *(const float4*)(wrow + k0 + kb + 4);
    bf16x8 bf;
    bf[0] = (short)f2bf(w0.x); bf[1] = (short)f2bf(w0.y);
    bf[2] = (short)f2bf(w0.z); bf[3] = (short)f2bf(w0.w);
    bf[4] = (short)f2bf(w1.x); bf[5] = (short)f2bf(w1.y);
    bf[6] = (short)f2bf(w1.z); bf[7] = (short)f2bf(w1.w);
    bf16x8 a0 = *(const bf16x8*)(ar0 + k0);
    bf16x8 a1 = *(const bf16x8*)(ar1 + k0);
    bf16x8 a2 = *(const bf16x8*)(ar2 + k0);
    bf16x8 a3 = *(const bf16x8*)(ar3 + k0);
    acc0 = __builtin_amdgcn_mfma_f32_16x16x32_bf16(a0, bf, acc0, 0, 0, 0);
    acc1 = __builtin_amdgcn_mfma_f32_16x16x32_bf16(a1, bf, acc1, 0, 0, 0);
    acc2 = __builtin_amdgcn_mfma_f32_16x16x32_bf16(a2, bf, acc2, 0, 0, 0);
    acc3 = __builtin_amdgcn_mfma_f32_16x16x32_bf16(a3, bf, acc3, 0, 0, 0);
  }
  if (valid) {
    float bias = bo[n];
    int rbase = (lane >> 4) * 4;
#pragma unroll
    for (int r = 0; r < 4; ++r) {
      out[(long)(0 * 16 + rbase + r) * Vdim + n] = tanhf(acc0[r] + bias);
      out[(long)(1 * 16 + rbase + r) * Vdim + n] = tanhf(acc1[r] + bias);
      out[(long)(2 * 16 + rbase + r) * Vdim + n] = tanhf(acc2[r] + bias);
      out[(long)(3 * 16 + rbase + r) * Vdim + n] = tanhf(acc3[r] + bias);
    }
  }
}

// ---------------- log_softmax stage 1: per-chunk online max/sumexp ----------
__global__ void k_lsm_part(const float* __restrict__ out, float* __restrict__ mlp) {
  int b = blockIdx.x, c = blockIdx.y;  // 4 chunks
  int tid = threadIdx.x;
  const int chunk = (Vdim + 3) / 4;
  int v0 = c * chunk, v1 = min(v0 + chunk, Vdim);
  const float* row = out + (long)b * Vdim;
  float m = -INFINITY, l = 0.f;
  for (int v = v0 + tid; v < v1; v += 256) {
    float x = row[v];
    float mn = fmaxf(m, x);
    l = l * __expf(m - mn) + __expf(x - mn);
    m = mn;
  }
#pragma unroll
  for (int off = 1; off < 64; off <<= 1) {
    float mo = __shfl_xor(m, off, 64);
    float lo = __shfl_xor(l, off, 64);
    float M = fmaxf(m, mo);
    l = l * __expf(m - M) + lo * __expf(mo - M);
    m = M;
  }
  __shared__ float sm[4], sl[4];
  if ((tid & 63) == 0) { sm[tid >> 6] = m; sl[tid >> 6] = l; }
  __syncthreads();
  if (tid == 0) {
    float M = fmaxf(fmaxf(sm[0], sm[1]), fmaxf(sm[2], sm[3]));
    float L = sl[0] * __expf(sm[0] - M) + sl[1] * __expf(sm[1] - M)
            + sl[2] * __expf(sm[2] - M) + sl[3] * __expf(sm[3] - M);
    mlp[((long)b * 4 + c) * 2] = M;
    mlp[((long)b * 4 + c) * 2 + 1] = L;
  }
}

// ---------------- log_softmax stage 2: subtract ----------------
__global__ void k_lsm_final(float* __restrict__ out, const float* __restrict__ mlp) {
  int b = blockIdx.x, c = blockIdx.y;  // 8 segments
  float M = -INFINITY;
#pragma unroll
  for (int i = 0; i < 4; ++i) M = fmaxf(M, mlp[((long)b * 4 + i) * 2]);
  float L = 0.f;
#pragma unroll
  for (int i = 0; i < 4; ++i)
    L += mlp[((long)b * 4 + i) * 2 + 1] * __expf(mlp[((long)b * 4 + i) * 2] - M);
  float lg = M + logf(L);
  const int seg = (Vdim + 7) / 8;
  int v0 = c * seg, v1 = min(v0 + seg, Vdim);
  float* row = out + (long)b * Vdim;
  for (int v = v0 + threadIdx.x; v < v1; v += 256) row[v] -= lg;
}

extern "C" void kernel_launch(void* const* d_in, const int* in_sizes, int n_in,
                              void* d_out, int out_size, void* d_ws, size_t ws_size,
                              hipStream_t stream) {
  const int* inputs   = (const int*)d_in[0];
  const float* hidden = (const float*)d_in[1];
  const float* context= (const float*)d_in[2];
  const float* enc    = (const float*)d_in[3];
  const float* E      = (const float*)d_in[4];
  const float* W_ih0  = (const float*)d_in[5];
  const float* W_hh0  = (const float*)d_in[6];
  const float* b_ih0  = (const float*)d_in[7];
  const float* b_hh0  = (const float*)d_in[8];
  const float* W_ih1  = (const float*)d_in[9];
  const float* W_hh1  = (const float*)d_in[10];
  const float* b_ih1  = (const float*)d_in[11];
  const float* b_hh1  = (const float*)d_in[12];
  const float* Wa     = (const float*)d_in[13];
  const float* ba     = (const float*)d_in[14];
  const float* Wo     = (const float*)d_in[15];
  const float* bo     = (const float*)d_in[16];

  float* ws = (float*)d_ws;
  float* x_buf   = ws;                         // 131072
  float* emb     = x_buf + 131072;             // 65536
  float* gi_part = emb + 65536;                // 8*196608 = 1572864
  float* gh_part = gi_part + 1572864;          // 4*196608 = 786432
  float* h0      = gh_part + 786432;           // 65536
  float* h1      = h0 + 65536;                 // 65536
  float* q_part  = h1 + 65536;                 // 8*65536 = 524288
  float* q       = q_part + 524288;            // 65536
  float* scoresp = q + 65536;                  // 131072
  float* cbp     = scoresp + 131072;           // 64
  float* ml      = cbp + 64;                   // 128
  float* lsmml   = ml + 128;                   // 512
  float* part    = lsmml + 512;                // 64*32*1028 = 2105344
  unsigned short* catb = (unsigned short*)(part + 2105344);  // 64*2048 bf16

  float* out0 = (float*)d_out;                       // [B, V]
  float* out1 = out0 + (size_t)Bdim * Vdim;          // [2, B, H]
  float* out2 = out1 + (size_t)2 * Bdim * Hdim;      // [B, H]
  float* out3 = out2 + (size_t)Bdim * Hdim;          // [B, T]

  k_embed_concat<<<256, 256, 0, stream>>>(inputs, E, context, x_buf, emb);

  // GRU layer 0
  k_gemm_sk<false><<<dim3(48, 8), 256, 0, stream>>>(x_buf, 2 * Hdim, W_ih0, 2 * Hdim, gi_part, 3 * Hdim, 3 * Hdim, 256);
  k_gemm_sk<false><<<dim3(48, 4), 256, 0, stream>>>(hidden, Hdim, W_hh0, Hdim, gh_part, 3 * Hdim, 3 * Hdim, 256);
  k_gru_gate2<<<256, 256, 0, stream>>>(gi_part, 8, gh_part, 4, b_ih0, b_hh0, hidden, h0);

  // GRU layer 1
  k_gemm_sk<false><<<dim3(48, 4), 256, 0, stream>>>(h0, Hdim, W_ih1, Hdim, gi_part, 3 * Hdim, 3 * Hdim, 256);
  k_gemm_sk<false><<<dim3(48, 4), 256, 0, stream>>>(hidden + Bdim * Hdim, Hdim, W_hh1, Hdim, gh_part, 3 * Hdim, 3 * Hdim, 256);
  k_gru_gate2<<<256, 256, 0, stream>>>(gi_part, 4, gh_part, 4, b_ih1, b_hh1, hidden + Bdim * Hdim, h1);

  k_hidden_out<<<512, 256, 0, stream>>>(h0, h1, emb, out1);
  k_h1_to_catb<<<64, 256, 0, stream>>>(h1, catb);

  // q = h1 @ Wa, split-K 8x128
  k_gemm_sk<true><<<dim3(16, 8), 256, 0, stream>>>(h1, Hdim, Wa, Hdim, q_part, Hdim, Hdim, 128);
  k_qcomb<<<256, 256, 0, stream>>>(q_part, q);
  k_cb<<<64, 256, 0, stream>>>(h1, ba, cbp);

  dim3 gsc(NCHUNK, Bdim);
  k_scores_ctx<<<gsc, 256, 0, stream>>>(enc, q, cbp, scoresp, part);
  k_ctx_combine<<<64, 256, 0, stream>>>(part, out2, catb, ml);
  k_attn<<<512, 256, 0, stream>>>(scoresp, ml, out3);

  // logits = tanh(catb @ Wo.T + bo) via bf16 MFMA, then two-stage log_softmax
  k_wo_mfma<<<786, 256, 0, stream>>>(catb, Wo, bo, out0);
  k_lsm_part<<<dim3(64, 4), 256, 0, stream>>>(out0, lsmml);
  k_lsm_final<<<dim3(64, 8), 256, 0, stream>>>(out0, lsmml);
}